// Round 15
// baseline (964.308 us; speedup 1.0000x reference)
//
#include <hip/hip_runtime.h>
#include <hip/hip_bf16.h>
#include <stdint.h>

// ---------------------------------------------------------------------------
// VarianceAdaptor on MI355X — round 15: r14 + 3 blocks/CU + masked-row k_out
// offload. LDS cut 56.5->53.8KB (bf16 LN partials; sm/sr aliased into the
// dead input-halo row 64 — NaN containment to discarded rows 62/63 verified).
// Skip blocks (t0>=mel, pitch side) write o_main rows (= pc2b+ec2b) so k_out
// only processes tiles with t0<mel.
// ---------------------------------------------------------------------------

using u16 = unsigned short;
using u32 = unsigned int;
typedef __attribute__((ext_vector_type(8))) short bf16x8;
typedef __attribute__((ext_vector_type(4))) float f32x4;

#define DEV static __device__ __forceinline__

DEV float bf2f(u16 u) { union { u32 i; float f; } v; v.i = ((u32)u) << 16; return v.f; }
DEV u16 f2bf(float f) {
  __hip_bfloat16 h = __float2bfloat16(f);      // HW RNE
  u16 u; __builtin_memcpy(&u, &h, 2); return u;
}
DEV float lof(u32 p) { union { u32 i; float f; } v; v.i = p << 16; return v.f; }
DEV float hif(u32 p) { union { u32 i; float f; } v; v.i = p & 0xFFFF0000u; return v.f; }

// ---- canonical bf16 scratch layout (element offsets) ------------------------
static constexpr int C_X    = 0;
static constexpr int C_SP   = 3145728;
static constexpr int C_SE   = 3153920;
static constexpr int C_DCW  = 3162112;
static constexpr int C_DCB  = 4046848;
static constexpr int C_DCG  = 4047616;
static constexpr int C_DCBE = 4048384;
static constexpr int C_DLW  = 4049152;
static constexpr int C_DLB  = 4049536;
static constexpr int C_PCW  = 4049544;
static constexpr int C_PCB  = 4934280;
static constexpr int C_PCG  = 4935048;
static constexpr int C_PCBE = 4935816;
static constexpr int C_PLW  = 4936584;
static constexpr int C_PLB  = 4936968;
static constexpr int C_ECW  = 4936976;
static constexpr int C_ECB  = 5821712;
static constexpr int C_ECG  = 5822480;
static constexpr int C_ECBE = 5823248;
static constexpr int C_ELW  = 5824016;
static constexpr int C_ELB  = 5824400;
static constexpr int C_PC1W = 5824408;
static constexpr int C_PC1B = 5824792;
static constexpr int C_EC1W = 5825176;
static constexpr int C_EC1B = 5825560;
static constexpr int C_PC2W = 5825944;
static constexpr int C_PC2B = 5826328;
static constexpr int C_EC2W = 5826712;
static constexpr int C_EC2B = 5827096;
static constexpr int C_END  = 5827480;

__device__ const int g_off[30] = {
  C_X, C_SP, C_SE, C_DCW, C_DCB, C_DCG, C_DCBE, C_DLW, C_DLB,
  C_PCW, C_PCB, C_PCG, C_PCBE, C_PLW, C_PLB,
  C_ECW, C_ECB, C_ECG, C_ECBE, C_ELW, C_ELB,
  C_PC1W, C_PC1B, C_EC1W, C_EC1B, C_PC2W, C_PC2B, C_EC2W, C_EC2B, C_END };
__device__ const int g_act[29] = {
  3145728, 8192, 8192, 884736, 768, 768, 768, 384, 1,
  884736, 768, 768, 768, 384, 1,
  884736, 768, 768, 768, 384, 1,
  384, 384, 384, 384, 384, 384, 384, 384 };

struct Srcs { const void* p[29]; };

struct BranchArgs {
  const u16 *S, *C1W, *C1B, *WF, *CB, *CG, *CBE, *LW, *LB;
  float* predF;
};

// ---- merged init (512 thr): ids 0..647 wprep | 648..663 prep | rest canon --
__global__ __launch_bounds__(512) void k_init(Srcs s, const int* __restrict__ dur,
    u16* __restrict__ canon, u16* __restrict__ WF,
    int* __restrict__ melLenI, int* __restrict__ idx,
    float* __restrict__ oDur, float* __restrict__ oML, float* __restrict__ oMask) {
  __shared__ int sh[512];
  const u32* x0 = (const u32*)s.p[0];
  int t = threadIdx.x, cnt = 0;
  for (int i = t; i < 2048; i += 512) {
    u32 wd = x0[i];
    u32 lo = wd & 0xFFFFu;
    float a = fabsf(lof(lo));
    if (lo == 0u || (a > 1e-5f && a < 1000.0f)) cnt++;
  }
  sh[t] = cnt; __syncthreads();
  for (int o = 256; o; o >>= 1) { if (t < o) sh[t] += sh[t + o]; __syncthreads(); }
  int isbf = (sh[0] > 1024) ? 1 : 0;
  __syncthreads();                              // sh reused below

  int id = blockIdx.x;
  if (id < 648) {                               // ---- wprep: 331776 threads
    int g = id * 512 + t;
    int l = g & 63; int rest = g >> 6;
    int nf = rest % 24; rest /= 24;
    int ks = rest % 36; rest /= 36;
    int ls = rest & 1;  int br = rest >> 1;
    if (br >= 3) return;
    const void* srcp = s.p[br == 0 ? 3 : (br == 1 ? 9 : 15)];  // d_cw/p_cw/e_cw
    int kk0 = ks * 32 + (l >> 4) * 8;
    int f = nf * 16 + (l & 15);
    u16* dst = WF + (size_t)br * 884736 + ((size_t)(ls * 36 + ks) * 24 + nf) * 512 + l * 8;
    #pragma unroll
    for (int j = 0; j < 8; ++j) {
      size_t li = (size_t)ls * 442368 + (size_t)(kk0 + j) * 384 + f;
      dst[j] = isbf ? ((const u16*)srcp)[li] : f2bf(((const float*)srcp)[li]);
    }
  } else if (id < 664) {                        // ---- prep (cumsum/idx/masks)
    int b = id - 648;
    int d = dur[b * 512 + t];
    sh[t] = d; __syncthreads();
    for (int o = 1; o < 512; o <<= 1) {
      int v = sh[t] + ((t >= o) ? sh[t - o] : 0);
      __syncthreads(); sh[t] = v; __syncthreads();
    }
    int mel = sh[511];
    if (t == 0) { melLenI[b] = mel; oML[b] = (float)mel; }
    oDur[b * 512 + t] = (float)d;
    for (int q = t; q < 4096; q += 512) {
      oMask[b * 4096 + q] = (q >= mel) ? 1.0f : 0.0f;
      int lo = 0, hi = 512;
      while (lo < hi) { int m = (lo + hi) >> 1; if (sh[m] <= q) lo = m + 1; else hi = m; }
      if (lo > 511) lo = 511;
      idx[b * 4096 + q] = lo;
    }
  } else {                                      // ---- canon
    int stride = 1384 * 512;
    for (int i = (id - 664) * 512 + t; i < C_END; i += stride) {
      int lo = 0, hi = 29;
      while (hi - lo > 1) { int m = (lo + hi) >> 1; if (i >= g_off[m]) lo = m; else hi = m; }
      int li = i - g_off[lo];
      u16 v = 0;
      if (li < g_act[lo]) {
        if (isbf) v = ((const u16*)s.p[lo])[li];
        else      v = f2bf(((const float*)s.p[lo])[li]);
      }
      canon[i] = v;
    }
  }
}

// ---- MFMA conv, N-split: wave owns 3 nf; B 2-slot register prefetch --------
template<int NMF>
DEV void conv_ns(const u16* sb, const u16* __restrict__ wf,
                 f32x4 (&acc)[NMF][3], const int* moff,
                 int w, int llo, int lhi, int l) {
  int arow = llo * 392 + lhi * 8;
  const u16* wb = wf + (3 * w) * 512 + l * 8;
  bf16x8 bb[2][3];
  #pragma unroll
  for (int j = 0; j < 3; ++j)
    bb[0][j] = *(const bf16x8*)(wb + j * 512);            // ks=0
  #pragma unroll
  for (int ks = 0; ks < 36; ++ks) {
    if (ks + 1 < 36) {
      #pragma unroll
      for (int j = 0; j < 3; ++j)
        bb[(ks + 1) & 1][j] = *(const bf16x8*)(wb + ((ks + 1) * 24 + j) * 512);
    }
    int k = ks / 12, c0 = (ks % 12) * 32;
    bf16x8 a[NMF];
    #pragma unroll
    for (int mf = 0; mf < NMF; ++mf)
      a[mf] = *(const bf16x8*)(sb + (moff[mf] + k) * 392 + c0 + arow);
    __builtin_amdgcn_s_setprio(1);
    #pragma unroll
    for (int mf = 0; mf < NMF; ++mf)
      #pragma unroll
      for (int j = 0; j < 3; ++j)
        acc[mf][j] = __builtin_amdgcn_mfma_f32_16x16x32_bf16(a[mf], bb[ks & 1][j], acc[mf][j], 0, 0, 0);
    __builtin_amdgcn_s_setprio(0);
  }
}

// ---- bias+relu+LN epilogue: bf16 partial stats; sm/sr aliased to row 64 ----
// Garbage from the alias feeds only input rows 64/65 -> output rows 62/63,
// which are discarded (per-row stats, h2 rows >= TT never read).
template<int NMF, bool ZERO_EDGE>
DEV void ln_ns(f32x4 (&acc)[NMF][3], const int* moff,
    const u16* __restrict__ CBp, const u16* __restrict__ CGp, const u16* __restrict__ CBEp,
    u16* sb, u16* sp1h, u16* sp2h,
    int w, int llo, int lhi, int tid, int t0, int L) {
  float* smf = (float*)(sb + 64 * 392);         // 256 B in dead halo row 64
  float* srf = smf + 64;                        // next 256 B
  int colb = w * 48 + llo;
  float bias[3], gv[3], bev[3];
  #pragma unroll
  for (int j = 0; j < 3; ++j) {
    bias[j] = bf2f(CBp[colb + j * 16]);
    gv[j]   = bf2f(CGp[colb + j * 16]);
    bev[j]  = bf2f(CBEp[colb + j * 16]);
  }
  #pragma unroll
  for (int mf = 0; mf < NMF; ++mf)
    #pragma unroll
    for (int j = 0; j < 3; ++j)
      #pragma unroll
      for (int r = 0; r < 4; ++r) {
        float v = acc[mf][j][r] + bias[j];
        acc[mf][j][r] = v > 0.f ? v : 0.f;
      }
  #pragma unroll
  for (int mf = 0; mf < NMF; ++mf)
    #pragma unroll
    for (int r = 0; r < 4; ++r) {
      float v0 = acc[mf][0][r], v1 = acc[mf][1][r], v2 = acc[mf][2][r];
      float p1 = v0 + v1 + v2;
      float p2 = v0 * v0 + v1 * v1 + v2 * v2;
      #pragma unroll
      for (int m = 1; m <= 8; m <<= 1) { p1 += __shfl_xor(p1, m); p2 += __shfl_xor(p2, m); }
      if (llo == 0) {
        int row = moff[mf] + lhi * 4 + r;
        sp1h[row * 8 + w] = f2bf(p1); sp2h[row * 8 + w] = f2bf(p2);
      }
    }
  __syncthreads();
  if (tid < 64) {
    float a = 0.f, bq = 0.f;
    #pragma unroll
    for (int q = 0; q < 8; ++q) { a += bf2f(sp1h[tid * 8 + q]); bq += bf2f(sp2h[tid * 8 + q]); }
    float m = a * (1.f / 384.f);
    float var = bq * (1.f / 384.f) - m * m; if (var < 0.f) var = 0.f;
    smf[tid] = m; srf[tid] = rsqrtf(var + 1e-5f);
  }
  __syncthreads();
  #pragma unroll
  for (int mf = 0; mf < NMF; ++mf)
    #pragma unroll
    for (int r = 0; r < 4; ++r) {
      int row = moff[mf] + lhi * 4 + r;
      float m = smf[row], rs = srf[row];
      bool valid = true;
      if (ZERO_EDGE) { int t = t0 - 1 + row; valid = (t >= 0) && (t < L); }
      #pragma unroll
      for (int j = 0; j < 3; ++j) {
        float v = (acc[mf][j][r] - m) * rs * gv[j] + bev[j];
        sb[row * 392 + colb + j * 16] = valid ? f2bf(v) : (u16)0;
      }
    }
  __syncthreads();
}

// ---------------------------------------------------------------------------
// Merged fused MFMA predictor. TT=62, 2288 blocks, 8 waves, N-split,
// 3 blocks/CU. ids 0..2143: pitch/energy (XCD remap); 2144+: duration.
// Fully-masked tiles: zero preds; pitch side also writes o_main rows.
// ---------------------------------------------------------------------------
__global__ __launch_bounds__(512, 6) void k_pred(
    const u16* __restrict__ X, const int* __restrict__ idx,
    const int* __restrict__ melLenI,
    BranchArgs arg0, BranchArgs arg1, BranchArgs arg2,
    const u16* __restrict__ PC2B, const u16* __restrict__ EC2B,
    float* __restrict__ o_main) {
  __shared__ alignas(16) u16 s_buf[66 * 392];         // 51,744 B (in/h1/h2; row64 hosts sm/sr)
  __shared__ u16 sp1h[64 * 8], sp2h[64 * 8];          // 2,048 B (bf16 partial stats)

  constexpr int TT = 62;
  int id = blockIdx.x;
  int zz, b, t0, L;
  bool mode1;
  if (id < 2144) {
    int xcd = id & 7, seq = id >> 3;                   // seq 0..267
    zz = xcd >> 2;                                     // branch per XCD half
    b  = (xcd & 3) * 4 + (seq & 3);                    // 4-batch group per XCD
    t0 = (seq >> 2) * TT;                              // 67 tiles
    L = 4096; mode1 = true;
  } else {
    int d = id - 2144;                                 // 0..143
    zz = 2; b = d & 15; t0 = (d >> 4) * TT;            // 9 tiles
    L = 512; mode1 = false;
  }
  const BranchArgs& ba = (zz == 0) ? arg0 : (zz == 1) ? arg1 : arg2;

  int tid = threadIdx.x;
  int w = tid >> 6, l = tid & 63;
  int llo = l & 15, lhi = l >> 4;
  int mel = melLenI[b];
  bool act = (l < 48);

  // --- masked-tile early-out (block-uniform; no barriers crossed) ---
  if (mode1 && t0 >= mel) {
    for (int q = tid; q < TT; q += 512) {
      int tt = t0 + q;
      if (tt < L) ba.predF[b * L + tt] = 0.f;
    }
    if (zz == 0) {                                    // pitch side owns o_main
      for (int q = tid; q < TT * 96; q += 512) {
        int r = q / 96, c = (q % 96) * 4;
        int tt = t0 + r;
        if (tt < L) {
          uint2 b1 = *(const uint2*)(PC2B + c);
          uint2 b2 = *(const uint2*)(EC2B + c);
          float4 o;
          o.x = lof(b1.x) + lof(b2.x);
          o.y = hif(b1.x) + hif(b2.x);
          o.z = lof(b1.y) + lof(b2.y);
          o.w = hif(b1.y) + hif(b2.y);
          *(float4*)(o_main + ((size_t)b * 4096 + tt) * 384 + c) = o;
        }
      }
    }
    return;
  }

  // --- provider: rows 0..65 (t = t0-2+r), 16B per active lane ---
  {
    bf16x8 c1w8 = {0,0,0,0,0,0,0,0}, c1b8 = {0,0,0,0,0,0,0,0};
    if (mode1 && act) {
      c1w8 = *(const bf16x8*)(ba.C1W + l * 8);
      c1b8 = *(const bf16x8*)(ba.C1B + l * 8);
    }
    for (int i = 0; i < 9; ++i) {
      int r = w + i * 8;
      if (r < 66) {
        int t = t0 - 2 + r;
        bool valid = (t >= 0) && (t < L) && (!mode1 || t < mel);
        int j = mode1 ? (valid ? idx[b * 4096 + t] : 0) : (valid ? t : 0);
        bf16x8 o8 = {0,0,0,0,0,0,0,0};
        if (act && valid) {
          bf16x8 xv = *(const bf16x8*)(X + ((size_t)b * 512 + j) * 384 + l * 8);
          if (mode1) {
            float sv = bf2f(ba.S[b * 512 + j]);
            #pragma unroll
            for (int q = 0; q < 8; ++q) {
              float v = bf2f((u16)xv[q]) + sv * bf2f((u16)c1w8[q]) + bf2f((u16)c1b8[q]);
              o8[q] = (short)f2bf(v);
            }
          } else o8 = xv;
        }
        if (act) *(bf16x8*)(s_buf + r * 392 + l * 8) = o8;
      }
    }
  }
  __syncthreads();

  const int moff[4] = {0, 16, 32, 48};

  // --- conv1 + LN (out rows 0..63 = t0-1 .. t0+62, exactly TT+2) ---
  {
    f32x4 acc1[4][3];
    #pragma unroll
    for (int mf = 0; mf < 4; ++mf)
      #pragma unroll
      for (int j = 0; j < 3; ++j) acc1[mf][j] = (f32x4){0.f, 0.f, 0.f, 0.f};
    conv_ns<4>(s_buf, ba.WF, acc1, moff, w, llo, lhi, l);
    ln_ns<4, true>(acc1, moff, ba.CB, ba.CG, ba.CBE, s_buf, sp1h, sp2h,
                   w, llo, lhi, tid, t0, L);
  }

  // --- conv2 + LN (out rows 0..63; rows 62,63 garbage, discarded) ---
  {
    f32x4 acc2[4][3];
    #pragma unroll
    for (int mf = 0; mf < 4; ++mf)
      #pragma unroll
      for (int j = 0; j < 3; ++j) acc2[mf][j] = (f32x4){0.f, 0.f, 0.f, 0.f};
    conv_ns<4>(s_buf, ba.WF + 442368, acc2, moff, w, llo, lhi, l);
    ln_ns<4, false>(acc2, moff, ba.CB + 384, ba.CG + 384, ba.CBE + 384, s_buf,
                    sp1h, sp2h, w, llo, lhi, tid, t0, L);
  }

  // --- linear 384->1 (+ mask), vectorized; only rows < TT and tt < L ---
  {
    bf16x8 lw8 = {0,0,0,0,0,0,0,0};
    if (act) lw8 = *(const bf16x8*)(ba.LW + l * 8);
    float lb = bf2f(ba.LB[0]);
    for (int i = 0; i < 8; ++i) {
      int r = w + i * 8;
      float s = 0.f;
      if (act) {
        bf16x8 h = *(const bf16x8*)(s_buf + r * 392 + l * 8);
        #pragma unroll
        for (int q = 0; q < 8; ++q) s += bf2f((u16)h[q]) * bf2f((u16)lw8[q]);
      }
      #pragma unroll
      for (int o = 32; o; o >>= 1) s += __shfl_xor(s, o);
      if (l == 0 && r < TT) {
        int tt = t0 + r;
        if (tt < L) {
          s += lb;
          if (mode1 && tt >= mel) s = 0.f;
          ba.predF[b * L + tt] = s;
        }
      }
    }
  }
}

// ---- final: out = x_exp + pp*pc2w + pc2b + ep*ec2w + ec2b  (f32 out) -------
// Rows in fully-masked tiles ((t/62)*62 >= mel) were written by k_pred.
__global__ __launch_bounds__(256) void k_out(const u16* __restrict__ X,
    const int* __restrict__ idx, const int* __restrict__ melLenI,
    const float* __restrict__ ppF, const float* __restrict__ epF,
    const u16* __restrict__ W1, const u16* __restrict__ B1,
    const u16* __restrict__ W2, const u16* __restrict__ B2,
    float* __restrict__ outp) {
  int i = blockIdx.x * 256 + threadIdx.x;      // float4 units
  int f4 = i % 96, row = i / 96;
  int b = row >> 12, t = row & 4095;
  int mel = melLenI[b];
  if ((t / 62) * 62 >= mel) return;            // tile handled by k_pred skip
  float pp = ppF[row], ep = epF[row];
  uint2 w1 = *(const uint2*)(W1 + f4 * 4);
  uint2 b1 = *(const uint2*)(B1 + f4 * 4);
  uint2 w2 = *(const uint2*)(W2 + f4 * 4);
  uint2 b2 = *(const uint2*)(B2 + f4 * 4);
  float xv[4] = {0.f, 0.f, 0.f, 0.f};
  if (t < mel) {
    int j = idx[row];
    uint2 xa = *(const uint2*)(X + (size_t)(b * 512 + j) * 384 + f4 * 4);
    xv[0] = lof(xa.x); xv[1] = hif(xa.x); xv[2] = lof(xa.y); xv[3] = hif(xa.y);
  }
  float4 o;
  o.x = xv[0] + pp * lof(w1.x) + lof(b1.x) + ep * lof(w2.x) + lof(b2.x);
  o.y = xv[1] + pp * hif(w1.x) + hif(b1.x) + ep * hif(w2.x) + hif(b2.x);
  o.z = xv[2] + pp * lof(w1.y) + lof(b1.y) + ep * lof(w2.y) + lof(b2.y);
  o.w = xv[3] + pp * hif(w1.y) + hif(b1.y) + ep * hif(w2.y) + hif(b2.y);
  *(float4*)(outp + (size_t)i * 4) = o;
}

// ---------------------------------------------------------------------------
extern "C" void kernel_launch(void* const* d_in, const int* in_sizes, int n_in,
                              void* d_out, int out_size, void* d_ws, size_t ws_size,
                              hipStream_t stream) {
  char* ws = (char*)d_ws;
  int*   melLenI = (int*)(ws + 33280);
  int*   idx     = (int*)(ws + 33536);
  u16*   canon   = (u16*)(ws + 295936);        // 11,654,960 B
  u16*   WF      = (u16*)(ws + 11950896);      //  5,308,416 B -> ~17.3 MB total

  float* o_main = (float*)d_out;               // (B, ML, H)
  float* o_pp   = o_main + 25165824;           // (B, ML)
  float* o_ep   = o_pp + 65536;                // (B, ML)
  float* o_ld   = o_ep + 65536;                // (B, T)
  float* o_dur  = o_ld + 8192;                 // (B, T)
  float* o_ml   = o_dur + 8192;                // (B,)
  float* o_mask = o_ml + 16;                   // (B, ML)

  Srcs S;
  static const int sel[29] = {0, 1, 2, 8, 9, 10, 11, 12, 13, 14, 15, 16, 17, 18, 19,
                              20, 21, 22, 23, 24, 25, 26, 27, 28, 29, 30, 31, 32, 33};
  for (int i = 0; i < 29; ++i) S.p[i] = d_in[sel[i]];
  const int* dur = (const int*)d_in[4];

  // init: wprep(648) + prep(16) + canon(1384) = 2048 blocks x 512
  k_init<<<2048, 512, 0, stream>>>(S, dur, canon, WF, melLenI, idx, o_dur, o_ml, o_mask);

  const u16* X = canon + C_X;

  BranchArgs aPit = { canon + C_SP, canon + C_PC1W, canon + C_PC1B,
                      WF + 1 * 884736, canon + C_PCB, canon + C_PCG, canon + C_PCBE,
                      canon + C_PLW, canon + C_PLB, o_pp };
  BranchArgs aEne = { canon + C_SE, canon + C_EC1W, canon + C_EC1B,
                      WF + 2 * 884736, canon + C_ECB, canon + C_ECG, canon + C_ECBE,
                      canon + C_ELW, canon + C_ELB, o_ep };
  BranchArgs aDur = { nullptr, nullptr, nullptr,
                      WF + 0 * 884736, canon + C_DCB, canon + C_DCG, canon + C_DCBE,
                      canon + C_DLW, canon + C_DLB, o_ld };

  // all three predictors in one launch (2144 p/e + 144 duration)
  k_pred<<<2288, 512, 0, stream>>>(X, idx, melLenI, aPit, aEne, aDur,
      canon + C_PC2B, canon + C_EC2B, o_main);

  // final assembly -> o_main (valid/partial tiles only)
  k_out<<<24576, 256, 0, stream>>>(X, idx, melLenI, o_pp, o_ep,
      canon + C_PC2W, canon + C_PC2B, canon + C_EC2W, canon + C_EC2B, o_main);
}

// Round 16
// 228.009 us; speedup vs baseline: 4.2293x; 4.2293x over previous
//
#include <hip/hip_runtime.h>
#include <hip/hip_bf16.h>
#include <stdint.h>

// ---------------------------------------------------------------------------
// VarianceAdaptor on MI355X — round 16: r14 (launch_bounds(512,4), f32 LN
// partials, 56.8KB LDS, 2 blocks/CU) + r15's good parts only: skip blocks
// write masked o_main rows; k_out guards those tiles out.
// r15 post-mortem: (512,6) -> 85-VGPR cap -> acc spill (VGPR 40, 700MB
// scratch writes, 964us). Occupancy squeeze is structurally infeasible.
// ---------------------------------------------------------------------------

using u16 = unsigned short;
using u32 = unsigned int;
typedef __attribute__((ext_vector_type(8))) short bf16x8;
typedef __attribute__((ext_vector_type(4))) float f32x4;

#define DEV static __device__ __forceinline__

DEV float bf2f(u16 u) { union { u32 i; float f; } v; v.i = ((u32)u) << 16; return v.f; }
DEV u16 f2bf(float f) {
  __hip_bfloat16 h = __float2bfloat16(f);      // HW RNE
  u16 u; __builtin_memcpy(&u, &h, 2); return u;
}
DEV float lof(u32 p) { union { u32 i; float f; } v; v.i = p << 16; return v.f; }
DEV float hif(u32 p) { union { u32 i; float f; } v; v.i = p & 0xFFFF0000u; return v.f; }

// ---- canonical bf16 scratch layout (element offsets) ------------------------
static constexpr int C_X    = 0;
static constexpr int C_SP   = 3145728;
static constexpr int C_SE   = 3153920;
static constexpr int C_DCW  = 3162112;
static constexpr int C_DCB  = 4046848;
static constexpr int C_DCG  = 4047616;
static constexpr int C_DCBE = 4048384;
static constexpr int C_DLW  = 4049152;
static constexpr int C_DLB  = 4049536;
static constexpr int C_PCW  = 4049544;
static constexpr int C_PCB  = 4934280;
static constexpr int C_PCG  = 4935048;
static constexpr int C_PCBE = 4935816;
static constexpr int C_PLW  = 4936584;
static constexpr int C_PLB  = 4936968;
static constexpr int C_ECW  = 4936976;
static constexpr int C_ECB  = 5821712;
static constexpr int C_ECG  = 5822480;
static constexpr int C_ECBE = 5823248;
static constexpr int C_ELW  = 5824016;
static constexpr int C_ELB  = 5824400;
static constexpr int C_PC1W = 5824408;
static constexpr int C_PC1B = 5824792;
static constexpr int C_EC1W = 5825176;
static constexpr int C_EC1B = 5825560;
static constexpr int C_PC2W = 5825944;
static constexpr int C_PC2B = 5826328;
static constexpr int C_EC2W = 5826712;
static constexpr int C_EC2B = 5827096;
static constexpr int C_END  = 5827480;

__device__ const int g_off[30] = {
  C_X, C_SP, C_SE, C_DCW, C_DCB, C_DCG, C_DCBE, C_DLW, C_DLB,
  C_PCW, C_PCB, C_PCG, C_PCBE, C_PLW, C_PLB,
  C_ECW, C_ECB, C_ECG, C_ECBE, C_ELW, C_ELB,
  C_PC1W, C_PC1B, C_EC1W, C_EC1B, C_PC2W, C_PC2B, C_EC2W, C_EC2B, C_END };
__device__ const int g_act[29] = {
  3145728, 8192, 8192, 884736, 768, 768, 768, 384, 1,
  884736, 768, 768, 768, 384, 1,
  884736, 768, 768, 768, 384, 1,
  384, 384, 384, 384, 384, 384, 384, 384 };

struct Srcs { const void* p[29]; };

struct BranchArgs {
  const u16 *S, *C1W, *C1B, *WF, *CB, *CG, *CBE, *LW, *LB;
  float* predF;
};

// ---- merged init (512 thr): ids 0..647 wprep | 648..663 prep | rest canon --
__global__ __launch_bounds__(512) void k_init(Srcs s, const int* __restrict__ dur,
    u16* __restrict__ canon, u16* __restrict__ WF,
    int* __restrict__ melLenI, int* __restrict__ idx,
    float* __restrict__ oDur, float* __restrict__ oML, float* __restrict__ oMask) {
  __shared__ int sh[512];
  const u32* x0 = (const u32*)s.p[0];
  int t = threadIdx.x, cnt = 0;
  for (int i = t; i < 2048; i += 512) {
    u32 wd = x0[i];
    u32 lo = wd & 0xFFFFu;
    float a = fabsf(lof(lo));
    if (lo == 0u || (a > 1e-5f && a < 1000.0f)) cnt++;
  }
  sh[t] = cnt; __syncthreads();
  for (int o = 256; o; o >>= 1) { if (t < o) sh[t] += sh[t + o]; __syncthreads(); }
  int isbf = (sh[0] > 1024) ? 1 : 0;
  __syncthreads();                              // sh reused below

  int id = blockIdx.x;
  if (id < 648) {                               // ---- wprep: 331776 threads
    int g = id * 512 + t;
    int l = g & 63; int rest = g >> 6;
    int nf = rest % 24; rest /= 24;
    int ks = rest % 36; rest /= 36;
    int ls = rest & 1;  int br = rest >> 1;
    if (br >= 3) return;
    const void* srcp = s.p[br == 0 ? 3 : (br == 1 ? 9 : 15)];  // d_cw/p_cw/e_cw
    int kk0 = ks * 32 + (l >> 4) * 8;
    int f = nf * 16 + (l & 15);
    u16* dst = WF + (size_t)br * 884736 + ((size_t)(ls * 36 + ks) * 24 + nf) * 512 + l * 8;
    #pragma unroll
    for (int j = 0; j < 8; ++j) {
      size_t li = (size_t)ls * 442368 + (size_t)(kk0 + j) * 384 + f;
      dst[j] = isbf ? ((const u16*)srcp)[li] : f2bf(((const float*)srcp)[li]);
    }
  } else if (id < 664) {                        // ---- prep (cumsum/idx/masks)
    int b = id - 648;
    int d = dur[b * 512 + t];
    sh[t] = d; __syncthreads();
    for (int o = 1; o < 512; o <<= 1) {
      int v = sh[t] + ((t >= o) ? sh[t - o] : 0);
      __syncthreads(); sh[t] = v; __syncthreads();
    }
    int mel = sh[511];
    if (t == 0) { melLenI[b] = mel; oML[b] = (float)mel; }
    oDur[b * 512 + t] = (float)d;
    for (int q = t; q < 4096; q += 512) {
      oMask[b * 4096 + q] = (q >= mel) ? 1.0f : 0.0f;
      int lo = 0, hi = 512;
      while (lo < hi) { int m = (lo + hi) >> 1; if (sh[m] <= q) lo = m + 1; else hi = m; }
      if (lo > 511) lo = 511;
      idx[b * 4096 + q] = lo;
    }
  } else {                                      // ---- canon
    int stride = 1384 * 512;
    for (int i = (id - 664) * 512 + t; i < C_END; i += stride) {
      int lo = 0, hi = 29;
      while (hi - lo > 1) { int m = (lo + hi) >> 1; if (i >= g_off[m]) lo = m; else hi = m; }
      int li = i - g_off[lo];
      u16 v = 0;
      if (li < g_act[lo]) {
        if (isbf) v = ((const u16*)s.p[lo])[li];
        else      v = f2bf(((const float*)s.p[lo])[li]);
      }
      canon[i] = v;
    }
  }
}

// ---- MFMA conv, N-split: wave owns 3 nf; B 2-slot register prefetch --------
template<int NMF>
DEV void conv_ns(const u16* sb, const u16* __restrict__ wf,
                 f32x4 (&acc)[NMF][3], const int* moff,
                 int w, int llo, int lhi, int l) {
  int arow = llo * 392 + lhi * 8;
  const u16* wb = wf + (3 * w) * 512 + l * 8;
  bf16x8 bb[2][3];
  #pragma unroll
  for (int j = 0; j < 3; ++j)
    bb[0][j] = *(const bf16x8*)(wb + j * 512);            // ks=0
  #pragma unroll
  for (int ks = 0; ks < 36; ++ks) {
    if (ks + 1 < 36) {
      #pragma unroll
      for (int j = 0; j < 3; ++j)
        bb[(ks + 1) & 1][j] = *(const bf16x8*)(wb + ((ks + 1) * 24 + j) * 512);
    }
    int k = ks / 12, c0 = (ks % 12) * 32;
    bf16x8 a[NMF];
    #pragma unroll
    for (int mf = 0; mf < NMF; ++mf)
      a[mf] = *(const bf16x8*)(sb + (moff[mf] + k) * 392 + c0 + arow);
    __builtin_amdgcn_s_setprio(1);
    #pragma unroll
    for (int mf = 0; mf < NMF; ++mf)
      #pragma unroll
      for (int j = 0; j < 3; ++j)
        acc[mf][j] = __builtin_amdgcn_mfma_f32_16x16x32_bf16(a[mf], bb[ks & 1][j], acc[mf][j], 0, 0, 0);
    __builtin_amdgcn_s_setprio(0);
  }
}

// ---- bias+relu+LN epilogue (N-split): stats across 8 waves via LDS ---------
template<int NMF, bool ZERO_EDGE>
DEV void ln_ns(f32x4 (&acc)[NMF][3], const int* moff,
    const u16* __restrict__ CBp, const u16* __restrict__ CGp, const u16* __restrict__ CBEp,
    u16* sb, float* sp1, float* sp2, float* sm, float* sr,
    int w, int llo, int lhi, int tid, int nrows, int t0, int L) {
  int colb = w * 48 + llo;
  float bias[3], gv[3], bev[3];
  #pragma unroll
  for (int j = 0; j < 3; ++j) {
    bias[j] = bf2f(CBp[colb + j * 16]);
    gv[j]   = bf2f(CGp[colb + j * 16]);
    bev[j]  = bf2f(CBEp[colb + j * 16]);
  }
  #pragma unroll
  for (int mf = 0; mf < NMF; ++mf)
    #pragma unroll
    for (int j = 0; j < 3; ++j)
      #pragma unroll
      for (int r = 0; r < 4; ++r) {
        float v = acc[mf][j][r] + bias[j];
        acc[mf][j][r] = v > 0.f ? v : 0.f;
      }
  #pragma unroll
  for (int mf = 0; mf < NMF; ++mf)
    #pragma unroll
    for (int r = 0; r < 4; ++r) {
      float v0 = acc[mf][0][r], v1 = acc[mf][1][r], v2 = acc[mf][2][r];
      float p1 = v0 + v1 + v2;
      float p2 = v0 * v0 + v1 * v1 + v2 * v2;
      #pragma unroll
      for (int m = 1; m <= 8; m <<= 1) { p1 += __shfl_xor(p1, m); p2 += __shfl_xor(p2, m); }
      if (llo == 0) {
        int row = moff[mf] + lhi * 4 + r;
        sp1[row * 8 + w] = p1; sp2[row * 8 + w] = p2;
      }
    }
  __syncthreads();
  if (tid < nrows) {
    float a = 0.f, bq = 0.f;
    #pragma unroll
    for (int q = 0; q < 8; ++q) { a += sp1[tid * 8 + q]; bq += sp2[tid * 8 + q]; }
    float m = a * (1.f / 384.f);
    float var = bq * (1.f / 384.f) - m * m; if (var < 0.f) var = 0.f;
    sm[tid] = m; sr[tid] = rsqrtf(var + 1e-5f);
  }
  __syncthreads();
  #pragma unroll
  for (int mf = 0; mf < NMF; ++mf)
    #pragma unroll
    for (int r = 0; r < 4; ++r) {
      int row = moff[mf] + lhi * 4 + r;
      float m = sm[row], rs = sr[row];
      bool valid = true;
      if (ZERO_EDGE) { int t = t0 - 1 + row; valid = (t >= 0) && (t < L); }
      #pragma unroll
      for (int j = 0; j < 3; ++j) {
        float v = (acc[mf][j][r] - m) * rs * gv[j] + bev[j];
        sb[row * 392 + colb + j * 16] = valid ? f2bf(v) : (u16)0;
      }
    }
  __syncthreads();
}

// ---------------------------------------------------------------------------
// Merged fused MFMA predictor. TT=62, 2288 blocks, 8 waves, N-split,
// 2 blocks/CU. ids 0..2143: pitch/energy (XCD remap); 2144+: duration.
// Fully-masked tiles: zero preds; pitch side also writes o_main rows.
// ---------------------------------------------------------------------------
__global__ __launch_bounds__(512, 4) void k_pred(
    const u16* __restrict__ X, const int* __restrict__ idx,
    const int* __restrict__ melLenI,
    BranchArgs arg0, BranchArgs arg1, BranchArgs arg2,
    const u16* __restrict__ PC2B, const u16* __restrict__ EC2B,
    float* __restrict__ o_main) {
  __shared__ alignas(16) u16 s_buf[66 * 392];         // 51,744 B (in/h1/h2)
  __shared__ float sp1[64 * 8], sp2[64 * 8];          // 4,096 B
  __shared__ float sm[64], sr[64];                    // 512 B

  constexpr int TT = 62;
  int id = blockIdx.x;
  int zz, b, t0, L;
  bool mode1;
  if (id < 2144) {
    int xcd = id & 7, seq = id >> 3;                   // seq 0..267
    zz = xcd >> 2;                                     // branch per XCD half
    b  = (xcd & 3) * 4 + (seq & 3);                    // 4-batch group per XCD
    t0 = (seq >> 2) * TT;                              // 67 tiles
    L = 4096; mode1 = true;
  } else {
    int d = id - 2144;                                 // 0..143
    zz = 2; b = d & 15; t0 = (d >> 4) * TT;            // 9 tiles
    L = 512; mode1 = false;
  }
  const BranchArgs& ba = (zz == 0) ? arg0 : (zz == 1) ? arg1 : arg2;

  int tid = threadIdx.x;
  int w = tid >> 6, l = tid & 63;
  int llo = l & 15, lhi = l >> 4;
  int mel = melLenI[b];
  bool act = (l < 48);

  // --- masked-tile early-out (block-uniform; no barriers crossed) ---
  if (mode1 && t0 >= mel) {
    for (int q = tid; q < TT; q += 512) {
      int tt = t0 + q;
      if (tt < L) ba.predF[b * L + tt] = 0.f;
    }
    if (zz == 0) {                                    // pitch side owns o_main
      for (int q = tid; q < TT * 96; q += 512) {
        int r = q / 96, c = (q % 96) * 4;
        int tt = t0 + r;
        if (tt < L) {
          uint2 b1 = *(const uint2*)(PC2B + c);
          uint2 b2 = *(const uint2*)(EC2B + c);
          float4 o;
          o.x = lof(b1.x) + lof(b2.x);
          o.y = hif(b1.x) + hif(b2.x);
          o.z = lof(b1.y) + lof(b2.y);
          o.w = hif(b1.y) + hif(b2.y);
          *(float4*)(o_main + ((size_t)b * 4096 + tt) * 384 + c) = o;
        }
      }
    }
    return;
  }

  // --- provider: rows 0..65 (t = t0-2+r), 16B per active lane ---
  {
    bf16x8 c1w8 = {0,0,0,0,0,0,0,0}, c1b8 = {0,0,0,0,0,0,0,0};
    if (mode1 && act) {
      c1w8 = *(const bf16x8*)(ba.C1W + l * 8);
      c1b8 = *(const bf16x8*)(ba.C1B + l * 8);
    }
    for (int i = 0; i < 9; ++i) {
      int r = w + i * 8;
      if (r < 66) {
        int t = t0 - 2 + r;
        bool valid = (t >= 0) && (t < L) && (!mode1 || t < mel);
        int j = mode1 ? (valid ? idx[b * 4096 + t] : 0) : (valid ? t : 0);
        bf16x8 o8 = {0,0,0,0,0,0,0,0};
        if (act && valid) {
          bf16x8 xv = *(const bf16x8*)(X + ((size_t)b * 512 + j) * 384 + l * 8);
          if (mode1) {
            float sv = bf2f(ba.S[b * 512 + j]);
            #pragma unroll
            for (int q = 0; q < 8; ++q) {
              float v = bf2f((u16)xv[q]) + sv * bf2f((u16)c1w8[q]) + bf2f((u16)c1b8[q]);
              o8[q] = (short)f2bf(v);
            }
          } else o8 = xv;
        }
        if (act) *(bf16x8*)(s_buf + r * 392 + l * 8) = o8;
      }
    }
  }
  __syncthreads();

  const int moff[4] = {0, 16, 32, 48};

  // --- conv1 + LN (out rows 0..63 = t0-1 .. t0+62, exactly TT+2) ---
  {
    f32x4 acc1[4][3];
    #pragma unroll
    for (int mf = 0; mf < 4; ++mf)
      #pragma unroll
      for (int j = 0; j < 3; ++j) acc1[mf][j] = (f32x4){0.f, 0.f, 0.f, 0.f};
    conv_ns<4>(s_buf, ba.WF, acc1, moff, w, llo, lhi, l);
    ln_ns<4, true>(acc1, moff, ba.CB, ba.CG, ba.CBE, s_buf, sp1, sp2, sm, sr,
                   w, llo, lhi, tid, 64, t0, L);
  }

  // --- conv2 + LN (out rows 0..63; rows 62,63 garbage, discarded) ---
  {
    f32x4 acc2[4][3];
    #pragma unroll
    for (int mf = 0; mf < 4; ++mf)
      #pragma unroll
      for (int j = 0; j < 3; ++j) acc2[mf][j] = (f32x4){0.f, 0.f, 0.f, 0.f};
    conv_ns<4>(s_buf, ba.WF + 442368, acc2, moff, w, llo, lhi, l);
    ln_ns<4, false>(acc2, moff, ba.CB + 384, ba.CG + 384, ba.CBE + 384, s_buf,
                    sp1, sp2, sm, sr, w, llo, lhi, tid, 64, t0, L);
  }

  // --- linear 384->1 (+ mask), vectorized; only rows < TT and tt < L ---
  {
    bf16x8 lw8 = {0,0,0,0,0,0,0,0};
    if (act) lw8 = *(const bf16x8*)(ba.LW + l * 8);
    float lb = bf2f(ba.LB[0]);
    for (int i = 0; i < 8; ++i) {
      int r = w + i * 8;
      float s = 0.f;
      if (act) {
        bf16x8 h = *(const bf16x8*)(s_buf + r * 392 + l * 8);
        #pragma unroll
        for (int q = 0; q < 8; ++q) s += bf2f((u16)h[q]) * bf2f((u16)lw8[q]);
      }
      #pragma unroll
      for (int o = 32; o; o >>= 1) s += __shfl_xor(s, o);
      if (l == 0 && r < TT) {
        int tt = t0 + r;
        if (tt < L) {
          s += lb;
          if (mode1 && tt >= mel) s = 0.f;
          ba.predF[b * L + tt] = s;
        }
      }
    }
  }
}

// ---- final: out = x_exp + pp*pc2w + pc2b + ep*ec2w + ec2b  (f32 out) -------
// Rows in fully-masked tiles ((t/62)*62 >= mel) were written by k_pred.
__global__ __launch_bounds__(256) void k_out(const u16* __restrict__ X,
    const int* __restrict__ idx, const int* __restrict__ melLenI,
    const float* __restrict__ ppF, const float* __restrict__ epF,
    const u16* __restrict__ W1, const u16* __restrict__ B1,
    const u16* __restrict__ W2, const u16* __restrict__ B2,
    float* __restrict__ outp) {
  int i = blockIdx.x * 256 + threadIdx.x;      // float4 units
  int f4 = i % 96, row = i / 96;
  int b = row >> 12, t = row & 4095;
  int mel = melLenI[b];
  if ((t / 62) * 62 >= mel) return;            // tile handled by k_pred skip
  float pp = ppF[row], ep = epF[row];
  uint2 w1 = *(const uint2*)(W1 + f4 * 4);
  uint2 b1 = *(const uint2*)(B1 + f4 * 4);
  uint2 w2 = *(const uint2*)(W2 + f4 * 4);
  uint2 b2 = *(const uint2*)(B2 + f4 * 4);
  float xv[4] = {0.f, 0.f, 0.f, 0.f};
  if (t < mel) {
    int j = idx[row];
    uint2 xa = *(const uint2*)(X + (size_t)(b * 512 + j) * 384 + f4 * 4);
    xv[0] = lof(xa.x); xv[1] = hif(xa.x); xv[2] = lof(xa.y); xv[3] = hif(xa.y);
  }
  float4 o;
  o.x = xv[0] + pp * lof(w1.x) + lof(b1.x) + ep * lof(w2.x) + lof(b2.x);
  o.y = xv[1] + pp * hif(w1.x) + hif(b1.x) + ep * hif(w2.x) + hif(b2.x);
  o.z = xv[2] + pp * lof(w1.y) + lof(b1.y) + ep * lof(w2.y) + lof(b2.y);
  o.w = xv[3] + pp * hif(w1.y) + hif(b1.y) + ep * hif(w2.y) + hif(b2.y);
  *(float4*)(outp + (size_t)i * 4) = o;
}

// ---------------------------------------------------------------------------
extern "C" void kernel_launch(void* const* d_in, const int* in_sizes, int n_in,
                              void* d_out, int out_size, void* d_ws, size_t ws_size,
                              hipStream_t stream) {
  char* ws = (char*)d_ws;
  int*   melLenI = (int*)(ws + 33280);
  int*   idx     = (int*)(ws + 33536);
  u16*   canon   = (u16*)(ws + 295936);        // 11,654,960 B
  u16*   WF      = (u16*)(ws + 11950896);      //  5,308,416 B -> ~17.3 MB total

  float* o_main = (float*)d_out;               // (B, ML, H)
  float* o_pp   = o_main + 25165824;           // (B, ML)
  float* o_ep   = o_pp + 65536;                // (B, ML)
  float* o_ld   = o_ep + 65536;                // (B, T)
  float* o_dur  = o_ld + 8192;                 // (B, T)
  float* o_ml   = o_dur + 8192;                // (B,)
  float* o_mask = o_ml + 16;                   // (B, ML)

  Srcs S;
  static const int sel[29] = {0, 1, 2, 8, 9, 10, 11, 12, 13, 14, 15, 16, 17, 18, 19,
                              20, 21, 22, 23, 24, 25, 26, 27, 28, 29, 30, 31, 32, 33};
  for (int i = 0; i < 29; ++i) S.p[i] = d_in[sel[i]];
  const int* dur = (const int*)d_in[4];

  // init: wprep(648) + prep(16) + canon(1384) = 2048 blocks x 512
  k_init<<<2048, 512, 0, stream>>>(S, dur, canon, WF, melLenI, idx, o_dur, o_ml, o_mask);

  const u16* X = canon + C_X;

  BranchArgs aPit = { canon + C_SP, canon + C_PC1W, canon + C_PC1B,
                      WF + 1 * 884736, canon + C_PCB, canon + C_PCG, canon + C_PCBE,
                      canon + C_PLW, canon + C_PLB, o_pp };
  BranchArgs aEne = { canon + C_SE, canon + C_EC1W, canon + C_EC1B,
                      WF + 2 * 884736, canon + C_ECB, canon + C_ECG, canon + C_ECBE,
                      canon + C_ELW, canon + C_ELB, o_ep };
  BranchArgs aDur = { nullptr, nullptr, nullptr,
                      WF + 0 * 884736, canon + C_DCB, canon + C_DCG, canon + C_DCBE,
                      canon + C_DLW, canon + C_DLB, o_ld };

  // all three predictors in one launch (2144 p/e + 144 duration)
  k_pred<<<2288, 512, 0, stream>>>(X, idx, melLenI, aPit, aEne, aDur,
      canon + C_PC2B, canon + C_EC2B, o_main);

  // final assembly -> o_main (valid/partial tiles only)
  k_out<<<24576, 256, 0, stream>>>(X, idx, melLenI, o_pp, o_ep,
      canon + C_PC2W, canon + C_PC2B, canon + C_EC2W, canon + C_EC2B, o_main);
}

// Round 17
// 191.737 us; speedup vs baseline: 5.0293x; 1.1892x over previous
//
#include <hip/hip_runtime.h>
#include <hip/hip_bf16.h>
#include <stdint.h>

// ---------------------------------------------------------------------------
// VarianceAdaptor on MI355X — round 17: r14 restored (216us config) + lean
// init: canon no longer copies the dead conv-weight regions (45% of its
// elements, unused since wprep reads d_in directly), X gets a direct
// vectorized copy path (no per-element binary search).
// r16 post-mortem: o_main offload into k_pred moved 56MB of writes into the
// tight kernel (k_pred 158->176us) for a smaller k_out saving -> reverted.
// ---------------------------------------------------------------------------

using u16 = unsigned short;
using u32 = unsigned int;
typedef __attribute__((ext_vector_type(8))) short bf16x8;
typedef __attribute__((ext_vector_type(4))) float f32x4;

#define DEV static __device__ __forceinline__

DEV float bf2f(u16 u) { union { u32 i; float f; } v; v.i = ((u32)u) << 16; return v.f; }
DEV u16 f2bf(float f) {
  __hip_bfloat16 h = __float2bfloat16(f);      // HW RNE
  u16 u; __builtin_memcpy(&u, &h, 2); return u;
}
DEV float lof(u32 p) { union { u32 i; float f; } v; v.i = p << 16; return v.f; }
DEV float hif(u32 p) { union { u32 i; float f; } v; v.i = p & 0xFFFF0000u; return v.f; }

// ---- canonical bf16 scratch layout (element offsets) ------------------------
static constexpr int C_X    = 0;
static constexpr int C_SP   = 3145728;
static constexpr int C_SE   = 3153920;
static constexpr int C_DCW  = 3162112;   // dead (wprep reads d_in) — not canon'd
static constexpr int C_DCB  = 4046848;
static constexpr int C_DCG  = 4047616;
static constexpr int C_DCBE = 4048384;
static constexpr int C_DLW  = 4049152;
static constexpr int C_DLB  = 4049536;
static constexpr int C_PCW  = 4049544;   // dead
static constexpr int C_PCB  = 4934280;
static constexpr int C_PCG  = 4935048;
static constexpr int C_PCBE = 4935816;
static constexpr int C_PLW  = 4936584;
static constexpr int C_PLB  = 4936968;
static constexpr int C_ECW  = 4936976;   // dead
static constexpr int C_ECB  = 5821712;
static constexpr int C_ECG  = 5822480;
static constexpr int C_ECBE = 5823248;
static constexpr int C_ELW  = 5824016;
static constexpr int C_ELB  = 5824400;
static constexpr int C_PC1W = 5824408;
static constexpr int C_PC1B = 5824792;
static constexpr int C_EC1W = 5825176;
static constexpr int C_EC1B = 5825560;
static constexpr int C_PC2W = 5825944;
static constexpr int C_PC2B = 5826328;
static constexpr int C_EC2W = 5826712;
static constexpr int C_EC2B = 5827096;
static constexpr int C_END  = 5827480;

__device__ const int g_off[30] = {
  C_X, C_SP, C_SE, C_DCW, C_DCB, C_DCG, C_DCBE, C_DLW, C_DLB,
  C_PCW, C_PCB, C_PCG, C_PCBE, C_PLW, C_PLB,
  C_ECW, C_ECB, C_ECG, C_ECBE, C_ELW, C_ELB,
  C_PC1W, C_PC1B, C_EC1W, C_EC1B, C_PC2W, C_PC2B, C_EC2W, C_EC2B, C_END };
__device__ const int g_act[29] = {
  3145728, 8192, 8192, 884736, 768, 768, 768, 384, 1,
  884736, 768, 768, 768, 384, 1,
  884736, 768, 768, 768, 384, 1,
  384, 384, 384, 384, 384, 384, 384, 384 };

struct Srcs { const void* p[29]; };

struct BranchArgs {
  const u16 *S, *C1W, *C1B, *WF, *CB, *CG, *CBE, *LW, *LB;
  float* predF;
};

// ---- merged init (512 thr, 1448 blocks):
//   0..647   wprep (fragment-swizzle weights from d_in)
//   648..663 prep  (cumsum/idx/masks)
//   664..1431 X copy (vectorized, direct index)
//   1432..1447 small params (4 compact ranges, binary search)
__global__ __launch_bounds__(512) void k_init(Srcs s, const int* __restrict__ dur,
    u16* __restrict__ canon, u16* __restrict__ WF,
    int* __restrict__ melLenI, int* __restrict__ idx,
    float* __restrict__ oDur, float* __restrict__ oML, float* __restrict__ oMask) {
  __shared__ int sh[512];
  const u32* x0 = (const u32*)s.p[0];
  int t = threadIdx.x, cnt = 0;
  for (int i = t; i < 2048; i += 512) {
    u32 wd = x0[i];
    u32 lo = wd & 0xFFFFu;
    float a = fabsf(lof(lo));
    if (lo == 0u || (a > 1e-5f && a < 1000.0f)) cnt++;
  }
  sh[t] = cnt; __syncthreads();
  for (int o = 256; o; o >>= 1) { if (t < o) sh[t] += sh[t + o]; __syncthreads(); }
  int isbf = (sh[0] > 1024) ? 1 : 0;
  __syncthreads();                              // sh reused below

  int id = blockIdx.x;
  if (id < 648) {                               // ---- wprep: 331776 threads
    int g = id * 512 + t;
    int l = g & 63; int rest = g >> 6;
    int nf = rest % 24; rest /= 24;
    int ks = rest % 36; rest /= 36;
    int ls = rest & 1;  int br = rest >> 1;
    if (br >= 3) return;
    const void* srcp = s.p[br == 0 ? 3 : (br == 1 ? 9 : 15)];  // d_cw/p_cw/e_cw
    int kk0 = ks * 32 + (l >> 4) * 8;
    int f = nf * 16 + (l & 15);
    u16* dst = WF + (size_t)br * 884736 + ((size_t)(ls * 36 + ks) * 24 + nf) * 512 + l * 8;
    #pragma unroll
    for (int j = 0; j < 8; ++j) {
      size_t li = (size_t)ls * 442368 + (size_t)(kk0 + j) * 384 + f;
      dst[j] = isbf ? ((const u16*)srcp)[li] : f2bf(((const float*)srcp)[li]);
    }
  } else if (id < 664) {                        // ---- prep (cumsum/idx/masks)
    int b = id - 648;
    int d = dur[b * 512 + t];
    sh[t] = d; __syncthreads();
    for (int o = 1; o < 512; o <<= 1) {
      int v = sh[t] + ((t >= o) ? sh[t - o] : 0);
      __syncthreads(); sh[t] = v; __syncthreads();
    }
    int mel = sh[511];
    if (t == 0) { melLenI[b] = mel; oML[b] = (float)mel; }
    oDur[b * 512 + t] = (float)d;
    for (int q = t; q < 4096; q += 512) {
      oMask[b * 4096 + q] = (q >= mel) ? 1.0f : 0.0f;
      int lo = 0, hi = 512;
      while (lo < hi) { int m = (lo + hi) >> 1; if (sh[m] <= q) lo = m + 1; else hi = m; }
      if (lo > 511) lo = 511;
      idx[b * 4096 + q] = lo;
    }
  } else if (id < 1432) {                       // ---- X copy (vectorized)
    int base = ((id - 664) * 512 + t) * 8;      // 0 .. 3145720
    if (isbf) {
      bf16x8 v = *(const bf16x8*)((const u16*)s.p[0] + base);
      *(bf16x8*)(canon + C_X + base) = v;
    } else {
      const float* xf = (const float*)s.p[0] + base;
      bf16x8 o;
      #pragma unroll
      for (int q = 0; q < 8; ++q) o[q] = (short)f2bf(xf[q]);
      *(bf16x8*)(canon + C_X + base) = o;
    }
  } else {                                      // ---- small params (27544 elems)
    for (int ci = (id - 1432) * 512 + t; ci < 27544; ci += 16 * 512) {
      int i;
      if (ci < 16384)      i = C_SP  + ci;              // SP+SE
      else if (ci < 19080) i = C_DCB + (ci - 16384);    // d biases/gains/lw
      else if (ci < 21776) i = C_PCB + (ci - 19080);    // p biases/gains/lw
      else                 i = C_ECB + (ci - 21776);    // e biases + 1x1 convs
      int lo = 0, hi = 29;
      while (hi - lo > 1) { int m = (lo + hi) >> 1; if (i >= g_off[m]) lo = m; else hi = m; }
      int li = i - g_off[lo];
      u16 v = 0;
      if (li < g_act[lo]) {
        if (isbf) v = ((const u16*)s.p[lo])[li];
        else      v = f2bf(((const float*)s.p[lo])[li]);
      }
      canon[i] = v;
    }
  }
}

// ---- MFMA conv, N-split: wave owns 3 nf; B 2-slot register prefetch --------
template<int NMF>
DEV void conv_ns(const u16* sb, const u16* __restrict__ wf,
                 f32x4 (&acc)[NMF][3], const int* moff,
                 int w, int llo, int lhi, int l) {
  int arow = llo * 392 + lhi * 8;
  const u16* wb = wf + (3 * w) * 512 + l * 8;
  bf16x8 bb[2][3];
  #pragma unroll
  for (int j = 0; j < 3; ++j)
    bb[0][j] = *(const bf16x8*)(wb + j * 512);            // ks=0
  #pragma unroll
  for (int ks = 0; ks < 36; ++ks) {
    if (ks + 1 < 36) {
      #pragma unroll
      for (int j = 0; j < 3; ++j)
        bb[(ks + 1) & 1][j] = *(const bf16x8*)(wb + ((ks + 1) * 24 + j) * 512);
    }
    int k = ks / 12, c0 = (ks % 12) * 32;
    bf16x8 a[NMF];
    #pragma unroll
    for (int mf = 0; mf < NMF; ++mf)
      a[mf] = *(const bf16x8*)(sb + (moff[mf] + k) * 392 + c0 + arow);
    __builtin_amdgcn_s_setprio(1);
    #pragma unroll
    for (int mf = 0; mf < NMF; ++mf)
      #pragma unroll
      for (int j = 0; j < 3; ++j)
        acc[mf][j] = __builtin_amdgcn_mfma_f32_16x16x32_bf16(a[mf], bb[ks & 1][j], acc[mf][j], 0, 0, 0);
    __builtin_amdgcn_s_setprio(0);
  }
}

// ---- bias+relu+LN epilogue (N-split): stats across 8 waves via LDS ---------
template<int NMF, bool ZERO_EDGE>
DEV void ln_ns(f32x4 (&acc)[NMF][3], const int* moff,
    const u16* __restrict__ CBp, const u16* __restrict__ CGp, const u16* __restrict__ CBEp,
    u16* sb, float* sp1, float* sp2, float* sm, float* sr,
    int w, int llo, int lhi, int tid, int nrows, int t0, int L) {
  int colb = w * 48 + llo;
  float bias[3], gv[3], bev[3];
  #pragma unroll
  for (int j = 0; j < 3; ++j) {
    bias[j] = bf2f(CBp[colb + j * 16]);
    gv[j]   = bf2f(CGp[colb + j * 16]);
    bev[j]  = bf2f(CBEp[colb + j * 16]);
  }
  #pragma unroll
  for (int mf = 0; mf < NMF; ++mf)
    #pragma unroll
    for (int j = 0; j < 3; ++j)
      #pragma unroll
      for (int r = 0; r < 4; ++r) {
        float v = acc[mf][j][r] + bias[j];
        acc[mf][j][r] = v > 0.f ? v : 0.f;
      }
  #pragma unroll
  for (int mf = 0; mf < NMF; ++mf)
    #pragma unroll
    for (int r = 0; r < 4; ++r) {
      float v0 = acc[mf][0][r], v1 = acc[mf][1][r], v2 = acc[mf][2][r];
      float p1 = v0 + v1 + v2;
      float p2 = v0 * v0 + v1 * v1 + v2 * v2;
      #pragma unroll
      for (int m = 1; m <= 8; m <<= 1) { p1 += __shfl_xor(p1, m); p2 += __shfl_xor(p2, m); }
      if (llo == 0) {
        int row = moff[mf] + lhi * 4 + r;
        sp1[row * 8 + w] = p1; sp2[row * 8 + w] = p2;
      }
    }
  __syncthreads();
  if (tid < nrows) {
    float a = 0.f, bq = 0.f;
    #pragma unroll
    for (int q = 0; q < 8; ++q) { a += sp1[tid * 8 + q]; bq += sp2[tid * 8 + q]; }
    float m = a * (1.f / 384.f);
    float var = bq * (1.f / 384.f) - m * m; if (var < 0.f) var = 0.f;
    sm[tid] = m; sr[tid] = rsqrtf(var + 1e-5f);
  }
  __syncthreads();
  #pragma unroll
  for (int mf = 0; mf < NMF; ++mf)
    #pragma unroll
    for (int r = 0; r < 4; ++r) {
      int row = moff[mf] + lhi * 4 + r;
      float m = sm[row], rs = sr[row];
      bool valid = true;
      if (ZERO_EDGE) { int t = t0 - 1 + row; valid = (t >= 0) && (t < L); }
      #pragma unroll
      for (int j = 0; j < 3; ++j) {
        float v = (acc[mf][j][r] - m) * rs * gv[j] + bev[j];
        sb[row * 392 + colb + j * 16] = valid ? f2bf(v) : (u16)0;
      }
    }
  __syncthreads();
}

// ---------------------------------------------------------------------------
// Merged fused MFMA predictor. TT=62, 2288 blocks, 8 waves, N-split,
// 2 blocks/CU. ids 0..2143: pitch/energy (XCD remap); 2144+: duration.
// Fully-masked pitch/energy tiles (t0 >= mel) early-out with a zero write.
// ---------------------------------------------------------------------------
__global__ __launch_bounds__(512, 4) void k_pred(
    const u16* __restrict__ X, const int* __restrict__ idx,
    const int* __restrict__ melLenI,
    BranchArgs arg0, BranchArgs arg1, BranchArgs arg2) {
  __shared__ alignas(16) u16 s_buf[66 * 392];         // 51,744 B (in/h1/h2)
  __shared__ float sp1[64 * 8], sp2[64 * 8];          // 4,096 B
  __shared__ float sm[64], sr[64];                    // 512 B

  constexpr int TT = 62;
  int id = blockIdx.x;
  int zz, b, t0, L;
  bool mode1;
  if (id < 2144) {
    int xcd = id & 7, seq = id >> 3;                   // seq 0..267
    zz = xcd >> 2;                                     // branch per XCD half
    b  = (xcd & 3) * 4 + (seq & 3);                    // 4-batch group per XCD
    t0 = (seq >> 2) * TT;                              // 67 tiles
    L = 4096; mode1 = true;
  } else {
    int d = id - 2144;                                 // 0..143
    zz = 2; b = d & 15; t0 = (d >> 4) * TT;            // 9 tiles
    L = 512; mode1 = false;
  }
  const BranchArgs& ba = (zz == 0) ? arg0 : (zz == 1) ? arg1 : arg2;

  int tid = threadIdx.x;
  int w = tid >> 6, l = tid & 63;
  int llo = l & 15, lhi = l >> 4;
  int mel = melLenI[b];
  bool act = (l < 48);

  // --- masked-tile early-out (block-uniform; no barriers crossed) ---
  if (mode1 && t0 >= mel) {
    for (int q = tid; q < TT; q += 512) {
      int tt = t0 + q;
      if (tt < L) ba.predF[b * L + tt] = 0.f;
    }
    return;
  }

  // --- provider: rows 0..65 (t = t0-2+r), 16B per active lane ---
  {
    bf16x8 c1w8 = {0,0,0,0,0,0,0,0}, c1b8 = {0,0,0,0,0,0,0,0};
    if (mode1 && act) {
      c1w8 = *(const bf16x8*)(ba.C1W + l * 8);
      c1b8 = *(const bf16x8*)(ba.C1B + l * 8);
    }
    for (int i = 0; i < 9; ++i) {
      int r = w + i * 8;
      if (r < 66) {
        int t = t0 - 2 + r;
        bool valid = (t >= 0) && (t < L) && (!mode1 || t < mel);
        int j = mode1 ? (valid ? idx[b * 4096 + t] : 0) : (valid ? t : 0);
        bf16x8 o8 = {0,0,0,0,0,0,0,0};
        if (act && valid) {
          bf16x8 xv = *(const bf16x8*)(X + ((size_t)b * 512 + j) * 384 + l * 8);
          if (mode1) {
            float sv = bf2f(ba.S[b * 512 + j]);
            #pragma unroll
            for (int q = 0; q < 8; ++q) {
              float v = bf2f((u16)xv[q]) + sv * bf2f((u16)c1w8[q]) + bf2f((u16)c1b8[q]);
              o8[q] = (short)f2bf(v);
            }
          } else o8 = xv;
        }
        if (act) *(bf16x8*)(s_buf + r * 392 + l * 8) = o8;
      }
    }
  }
  __syncthreads();

  const int moff[4] = {0, 16, 32, 48};

  // --- conv1 + LN (out rows 0..63 = t0-1 .. t0+62, exactly TT+2) ---
  {
    f32x4 acc1[4][3];
    #pragma unroll
    for (int mf = 0; mf < 4; ++mf)
      #pragma unroll
      for (int j = 0; j < 3; ++j) acc1[mf][j] = (f32x4){0.f, 0.f, 0.f, 0.f};
    conv_ns<4>(s_buf, ba.WF, acc1, moff, w, llo, lhi, l);
    ln_ns<4, true>(acc1, moff, ba.CB, ba.CG, ba.CBE, s_buf, sp1, sp2, sm, sr,
                   w, llo, lhi, tid, 64, t0, L);
  }

  // --- conv2 + LN (out rows 0..63; rows 62,63 garbage, discarded) ---
  {
    f32x4 acc2[4][3];
    #pragma unroll
    for (int mf = 0; mf < 4; ++mf)
      #pragma unroll
      for (int j = 0; j < 3; ++j) acc2[mf][j] = (f32x4){0.f, 0.f, 0.f, 0.f};
    conv_ns<4>(s_buf, ba.WF + 442368, acc2, moff, w, llo, lhi, l);
    ln_ns<4, false>(acc2, moff, ba.CB + 384, ba.CG + 384, ba.CBE + 384, s_buf,
                    sp1, sp2, sm, sr, w, llo, lhi, tid, 64, t0, L);
  }

  // --- linear 384->1 (+ mask), vectorized; only rows < TT and tt < L ---
  {
    bf16x8 lw8 = {0,0,0,0,0,0,0,0};
    if (act) lw8 = *(const bf16x8*)(ba.LW + l * 8);
    float lb = bf2f(ba.LB[0]);
    for (int i = 0; i < 8; ++i) {
      int r = w + i * 8;
      float s = 0.f;
      if (act) {
        bf16x8 h = *(const bf16x8*)(s_buf + r * 392 + l * 8);
        #pragma unroll
        for (int q = 0; q < 8; ++q) s += bf2f((u16)h[q]) * bf2f((u16)lw8[q]);
      }
      #pragma unroll
      for (int o = 32; o; o >>= 1) s += __shfl_xor(s, o);
      if (l == 0 && r < TT) {
        int tt = t0 + r;
        if (tt < L) {
          s += lb;
          if (mode1 && tt >= mel) s = 0.f;
          ba.predF[b * L + tt] = s;
        }
      }
    }
  }
}

// ---- final: out = x_exp + pp*pc2w + pc2b + ep*ec2w + ec2b  (f32 out) -------
__global__ __launch_bounds__(256) void k_out(const u16* __restrict__ X,
    const int* __restrict__ idx, const int* __restrict__ melLenI,
    const float* __restrict__ ppF, const float* __restrict__ epF,
    const u16* __restrict__ W1, const u16* __restrict__ B1,
    const u16* __restrict__ W2, const u16* __restrict__ B2,
    float* __restrict__ outp) {
  int i = blockIdx.x * 256 + threadIdx.x;      // float4 units
  int f4 = i % 96, row = i / 96;
  int b = row >> 12, t = row & 4095;
  float pp = ppF[row], ep = epF[row];
  uint2 w1 = *(const uint2*)(W1 + f4 * 4);
  uint2 b1 = *(const uint2*)(B1 + f4 * 4);
  uint2 w2 = *(const uint2*)(W2 + f4 * 4);
  uint2 b2 = *(const uint2*)(B2 + f4 * 4);
  float xv[4] = {0.f, 0.f, 0.f, 0.f};
  if (t < melLenI[b]) {
    int j = idx[row];
    uint2 xa = *(const uint2*)(X + (size_t)(b * 512 + j) * 384 + f4 * 4);
    xv[0] = lof(xa.x); xv[1] = hif(xa.x); xv[2] = lof(xa.y); xv[3] = hif(xa.y);
  }
  float4 o;
  o.x = xv[0] + pp * lof(w1.x) + lof(b1.x) + ep * lof(w2.x) + lof(b2.x);
  o.y = xv[1] + pp * hif(w1.x) + hif(b1.x) + ep * hif(w2.x) + hif(b2.x);
  o.z = xv[2] + pp * lof(w1.y) + lof(b1.y) + ep * lof(w2.y) + lof(b2.y);
  o.w = xv[3] + pp * hif(w1.y) + hif(b1.y) + ep * hif(w2.y) + hif(b2.y);
  *(float4*)(outp + (size_t)i * 4) = o;
}

// ---------------------------------------------------------------------------
extern "C" void kernel_launch(void* const* d_in, const int* in_sizes, int n_in,
                              void* d_out, int out_size, void* d_ws, size_t ws_size,
                              hipStream_t stream) {
  char* ws = (char*)d_ws;
  int*   melLenI = (int*)(ws + 33280);
  int*   idx     = (int*)(ws + 33536);
  u16*   canon   = (u16*)(ws + 295936);        // 11,654,960 B
  u16*   WF      = (u16*)(ws + 11950896);      //  5,308,416 B -> ~17.3 MB total

  float* o_main = (float*)d_out;               // (B, ML, H)
  float* o_pp   = o_main + 25165824;           // (B, ML)
  float* o_ep   = o_pp + 65536;                // (B, ML)
  float* o_ld   = o_ep + 65536;                // (B, T)
  float* o_dur  = o_ld + 8192;                 // (B, T)
  float* o_ml   = o_dur + 8192;                // (B,)
  float* o_mask = o_ml + 16;                   // (B, ML)

  Srcs S;
  static const int sel[29] = {0, 1, 2, 8, 9, 10, 11, 12, 13, 14, 15, 16, 17, 18, 19,
                              20, 21, 22, 23, 24, 25, 26, 27, 28, 29, 30, 31, 32, 33};
  for (int i = 0; i < 29; ++i) S.p[i] = d_in[sel[i]];
  const int* dur = (const int*)d_in[4];

  // init: wprep(648) + prep(16) + Xcopy(768) + small(16) = 1448 blocks x 512
  k_init<<<1448, 512, 0, stream>>>(S, dur, canon, WF, melLenI, idx, o_dur, o_ml, o_mask);

  const u16* X = canon + C_X;

  BranchArgs aPit = { canon + C_SP, canon + C_PC1W, canon + C_PC1B,
                      WF + 1 * 884736, canon + C_PCB, canon + C_PCG, canon + C_PCBE,
                      canon + C_PLW, canon + C_PLB, o_pp };
  BranchArgs aEne = { canon + C_SE, canon + C_EC1W, canon + C_EC1B,
                      WF + 2 * 884736, canon + C_ECB, canon + C_ECG, canon + C_ECBE,
                      canon + C_ELW, canon + C_ELB, o_ep };
  BranchArgs aDur = { nullptr, nullptr, nullptr,
                      WF + 0 * 884736, canon + C_DCB, canon + C_DCG, canon + C_DCBE,
                      canon + C_DLW, canon + C_DLB, o_ld };

  // all three predictors in one launch (2144 p/e + 144 duration)
  k_pred<<<2288, 512, 0, stream>>>(X, idx, melLenI, aPit, aEne, aDur);

  // final assembly -> o_main
  k_out<<<24576, 256, 0, stream>>>(X, idx, melLenI, o_pp, o_ep,
      canon + C_PC2W, canon + C_PC2B, canon + C_EC2W, canon + C_EC2B, o_main);
}